// Round 14
// baseline (2464.690 us; speedup 1.0000x reference)
//
#include <hip/hip_runtime.h>
#include <hip/hip_bf16.h>

typedef unsigned short u16;
typedef __attribute__((ext_vector_type(8))) short bf16x8;
typedef __attribute__((ext_vector_type(8))) u16   u16x8;
typedef __attribute__((ext_vector_type(4))) float f32x4;

#define T_STEPS 256
#define BATCH   128
#define INDIM   512
#define HDIM    1024
#define GDIM    4096
#define KTOT    1536

#define OFF_XBF   ((size_t)0)
#define XBF_BYTES ((size_t)T_STEPS * BATCH * INDIM * 2)   // 33554432 (fragment-order)
#define OFF_BM    (OFF_XBF + XBF_BYTES)
#define BM_BYTES  ((size_t)2 * GDIM * KTOT * 2)           // 25165824
#define OFF_BIAS  (OFF_BM + BM_BYTES)
#define BIAS_BYTES ((size_t)2 * GDIM * 4)                 // 32768
#define OFF_CNT   (OFF_BIAS + BIAS_BYTES)
#define OFF_ROLL  (OFF_CNT + 8192)
#define ROLL_BYTES ((size_t)(T_STEPS + 1) * 2 * BATCH * HDIM * 2)  // 134742016
#define WS_NEED   (OFF_ROLL + ROLL_BYTES)

// h roll: slot s has 4 blocks [dir][mt] of 65536 elems (64 rows x 1024 cols,
// MFMA-fragment order): elem = (((kq*8+ks)*4+mi)*64 + h4*16+ar)*8 + e
//   <-> h[row = mt*64 + 16*mi + ar][col = 256*kq + 32*ks + 8*h4 + e]

__device__ __forceinline__ u16 f2b(float f) {
  __hip_bfloat16 h = __float2bfloat16(f);
  return *reinterpret_cast<u16*>(&h);
}

// ---------------- prepass: shuffle x (f32) into bf16 MFMA-fragment order ----
// xs block per (t,mt): 32768 elems; elem = (((kq*4+ksx)*4+mi)*64 + h4*16+ar)*8 + e
__global__ void k_cast_x(const float* __restrict__ x, u16* __restrict__ xs) {
  int i = blockIdx.x * 256 + threadIdx.x;      // one 8-elem fragment per thread
  int t   = i >> 13;                           // 8192 frags per t
  int r13 = i & 8191;
  int row = r13 >> 6;                          // 0..127
  int c0  = (r13 & 63) * 8;                    // 0..504
  int mt = row >> 6, rloc = row & 63;
  int mi = rloc >> 4, ar = rloc & 15;
  int kq = c0 >> 7, ksx = (c0 >> 5) & 3, h4 = (c0 & 31) >> 3;
  const float* src = x + ((size_t)t * BATCH + row) * INDIM + c0;
  f32x4 a = *reinterpret_cast<const f32x4*>(src);
  f32x4 b = *reinterpret_cast<const f32x4*>(src + 4);
  u16x8 u;
  u[0] = f2b(a[0]); u[1] = f2b(a[1]); u[2] = f2b(a[2]); u[3] = f2b(a[3]);
  u[4] = f2b(b[0]); u[5] = f2b(b[1]); u[6] = f2b(b[2]); u[7] = f2b(b[3]);
  size_t dst = ((size_t)(t * 2 + mt)) * 32768
             + (((size_t)((kq * 4 + ksx) * 4 + mi)) * 64 + h4 * 16 + ar) * 8;
  *reinterpret_cast<u16x8*>(xs + dst) = u;
}

// ---------------- prepass: build merged weight matrix ----------------
// Bm[dir][jt][c 0..63][k 0..1535]; c -> G = (c>>4)*1024 + jt*16 + (c&15)
__global__ void k_build_b(const float* __restrict__ Whh_f, const float* __restrict__ Wih_f,
                          const float* __restrict__ Whh_r, const float* __restrict__ Wih_r,
                          u16* __restrict__ Bm) {
  int blk = blockIdx.x;              // 0..127 = dir*64 + jt
  int dir = blk >> 6, jt = blk & 63;
  const float* Whh = dir ? Whh_r : Whh_f;
  const float* Wih = dir ? Wih_r : Wih_f;
  u16* dst = Bm + (size_t)blk * 64 * KTOT;
  for (int c = 0; c < 64; c++) {
    int G = (c >> 4) * HDIM + jt * 16 + (c & 15);
    for (int k = threadIdx.x; k < KTOT; k += 256) {
      float v = (k < HDIM) ? Whh[(size_t)G * HDIM + k] : Wih[(size_t)G * INDIM + (k - HDIM)];
      dst[c * KTOT + k] = f2b(v);
    }
  }
}

// ---------------- prepass: init roll slot 0 (fragment order), bias, flags ----
__global__ void k_init(const float* __restrict__ h0f, const float* __restrict__ h0r,
                       const float* __restrict__ bihf, const float* __restrict__ bhhf,
                       const float* __restrict__ bihr, const float* __restrict__ bhhr,
                       u16* __restrict__ hfrag, float* __restrict__ bias,
                       unsigned* __restrict__ flags) {
  int i = blockIdx.x * 256 + threadIdx.x;
  if (i < 2 * BATCH * HDIM) {
    int dir = i / (BATCH * HDIM);
    int rem = i - dir * BATCH * HDIM;
    int r = rem / HDIM, c = rem - r * HDIM;
    int mt = r >> 6, rloc = r & 63;
    int mi = rloc >> 4, ar = rloc & 15;
    int kq = c >> 8, ks = (c >> 5) & 7, h4 = (c & 31) >> 3, e = c & 7;
    const float* h0 = dir ? h0r : h0f;
    size_t off = ((size_t)(dir * 2 + mt)) * 65536
               + (((size_t)((kq * 8 + ks) * 4 + mi)) * 64 + h4 * 16 + ar) * 8 + e;
    hfrag[off] = f2b(h0[rem]);
  }
  if (i < 2 * GDIM) {
    int dir = i / GDIM, g = i - dir * GDIM;
    bias[i] = dir ? (bihr[g] + bhhr[g]) : (bihf[g] + bhhf[g]);
  }
  if (i < 512) flags[i] = 0;
}

// ---------------- persistent bidirectional LSTM ----------------
// grid 256 x 512 (1 WG/CU). NEW MAPPING: XCD = (dir, col-quarter p) owns gate
// cols for h-cols [256p,+256): weight panel 3.1MB -> L2-RESIDENT per XCD.
// 32 WGs/XCD = (jt_local 0..15) x (mt 0..1). WG: M=64 x N=64 x K=1536; 8 waves
// = 4 K-split x 2 N-split; bh 64 VGPR/wave, bx in LDS. h fragment-ordered via
// LLC (cross-XCD): wave kq consumes exactly XCD kq's slice -> polls 16 flags.
__global__ __launch_bounds__(512, 2) void k_lstm(
    const u16* __restrict__ xs, const u16* __restrict__ Bm,
    u16* __restrict__ hfrag,
    const float* __restrict__ bias, unsigned* __restrict__ flags,
    const float* __restrict__ c0f, const float* __restrict__ c0r,
    float* __restrict__ out) {
  __shared__ char ldsAll[70656 + 65536];   // partials [4][64][69] f32 | bx 64KB
  float* ldsP = reinterpret_cast<float*>(ldsAll);
  char* bxl = ldsAll + 70656;

  // Invalidate stale L1/L2 lines from a previous graph replay.
  __builtin_amdgcn_fence(__ATOMIC_ACQUIRE, "agent");

  const int wg    = blockIdx.x;
  const int xcd   = wg & 7;                    // round-robin XCD dispatch
  const int dir   = xcd >> 2, p = xcd & 3;     // direction, col-quarter owner
  const int local = wg >> 3;                   // 0..31 within XCD
  const int mt    = local >> 4;                // batch half
  const int jtl   = local & 15;                // local jt block
  const int jt    = p * 16 + jtl;              // global jt 0..63
  const int tid  = threadIdx.x;
  const int w = tid >> 6, lane = tid & 63;
  const int kq = w >> 1, nh = w & 1;           // 4-way K x 2-way N
  const int h4 = lane >> 4, kk = h4 * 8;
  const int ar = lane & 15;

  // ---- resident h-part weights: 16 frags = 64 VGPR (panel is L2-local) ----
  const u16* bsrc = Bm + (size_t)(dir * 64 + jt) * 64 * KTOT;
  bf16x8 bh[8][2];
#pragma unroll
  for (int ks = 0; ks < 8; ks++)
#pragma unroll
    for (int ni = 0; ni < 2; ni++)
      bh[ks][ni] = *reinterpret_cast<const bf16x8*>(
          bsrc + (size_t)(nh * 32 + ni * 16 + ar) * KTOT + 256 * kq + 32 * ks + kk);

  // ---- stage x-part weights into LDS (once), fragment layout ----
#pragma unroll
  for (int i = 0; i < 8; i++) {
    int fid = i * 8 + w;                       // 0..63
    int kq2 = fid >> 4, ksx2 = (fid >> 2) & 3, nh2 = (fid >> 1) & 1, ni2 = fid & 1;
    bf16x8 v = *reinterpret_cast<const bf16x8*>(
        bsrc + (size_t)(nh2 * 32 + ni2 * 16 + ar) * KTOT + HDIM + 128 * kq2 + 32 * ksx2 + kk);
    *reinterpret_cast<bf16x8*>(bxl + ((size_t)fid * 64 + lane) * 16) = v;
  }

  // ---- gating thread mapping: 1 row x 2 adjacent h-cols ----
  const int rrow = tid >> 3;            // 0..63 local row
  const int jl0  = 2 * (tid & 7);       // 0..14 even
  const int row0 = mt * 64 + rrow;      // global batch row
  const int jg0  = jt * 16 + jl0;       // global h column (even)
  const float* c0 = dir ? c0r : c0f;
  float2 cc = *reinterpret_cast<const float2*>(c0 + (size_t)row0 * HDIM + jg0);
  float cst0 = cc.x, cst1 = cc.y;
  const float2 b_i = *reinterpret_cast<const float2*>(bias + dir * GDIM + 0 * HDIM + jg0);
  const float2 b_f = *reinterpret_cast<const float2*>(bias + dir * GDIM + 1 * HDIM + jg0);
  const float2 b_g = *reinterpret_cast<const float2*>(bias + dir * GDIM + 2 * HDIM + jg0);
  const float2 b_o = *reinterpret_cast<const float2*>(bias + dir * GDIM + 3 * HDIM + jg0);

  // publish position (fragment order): this thread owns (row0, jg0, jg0+1)
  const size_t poff = (((size_t)(((jg0 >> 8) * 8 + ((jg0 >> 5) & 7)) * 4 + (rrow >> 4))) * 64
                       + ((jg0 & 31) >> 3) * 16 + (rrow & 15)) * 8 + (jg0 & 7);

  // wave kq consumes h-cols [256kq,+256) = XCD (dir,kq)'s output, rows of mt:
  // poll its 16 producer WGs (jt_local 0..15, same mt).
  const unsigned* fpw = flags + ((dir * 4 + kq) * 16 + (lane & 15)) * 2 + mt;
  // producer flag of this WG
  unsigned* mypost = flags + ((dir * 4 + p) * 16 + jtl) * 2 + mt;

  __syncthreads();   // bx staged

#pragma unroll 1
  for (int s = 0; s < T_STEPS; s++) {
    const int t = dir ? (T_STEPS - 1 - s) : s;

    // ---- x fragment loads (coalesced 1KB bursts), before the wait ----
    bf16x8 ax[4][4];
    {
      const u16* xb = xs + ((size_t)(t * 2 + mt)) * 32768;
#pragma unroll
      for (int ksx = 0; ksx < 4; ksx++)
#pragma unroll
        for (int mi = 0; mi < 4; mi++)
          ax[ksx][mi] = *reinterpret_cast<const bf16x8*>(
              xb + (((size_t)((kq * 4 + ksx) * 4 + mi)) * 64 + lane) * 8);
    }

    // ---- fine-grained wait: this wave's 16 producers (one XCD's slice) ----
    if (s > 0) {
      while (true) {
        unsigned f = __hip_atomic_load(fpw, __ATOMIC_RELAXED, __HIP_MEMORY_SCOPE_AGENT);
        if (__all((int)(f >= (unsigned)s))) break;
        __builtin_amdgcn_s_sleep(1);
      }
      __builtin_amdgcn_sched_barrier(0);   // keep h loads below the wait
    }

    f32x4 acc[4][2];
#pragma unroll
    for (int mi = 0; mi < 4; mi++)
#pragma unroll
      for (int ni = 0; ni < 2; ni++) acc[mi][ni] = f32x4{0.f, 0.f, 0.f, 0.f};

    const u16* hB = hfrag + ((size_t)(s * 4 + dir * 2 + mt)) * 65536;
    bf16x8 ahA[2][4], ahB[2][4];

#define LOADQ(BUF, G)                                                          \
  {                                                                            \
    _Pragma("unroll")                                                          \
    for (int k2 = 0; k2 < 2; k2++)                                             \
      _Pragma("unroll")                                                        \
      for (int mi = 0; mi < 4; mi++)                                           \
        BUF[k2][mi] = *reinterpret_cast<const bf16x8*>(                        \
            hB + (((size_t)((kq * 8 + 2 * (G) + k2) * 4 + mi)) * 64 + lane) * 8); \
  }
#define MFMAQ(BUF, G)                                                          \
  {                                                                            \
    _Pragma("unroll")                                                          \
    for (int k2 = 0; k2 < 2; k2++)                                             \
      _Pragma("unroll")                                                        \
      for (int mi = 0; mi < 4; mi++)                                           \
        _Pragma("unroll")                                                      \
        for (int ni = 0; ni < 2; ni++)                                         \
          acc[mi][ni] = __builtin_amdgcn_mfma_f32_16x16x32_bf16(               \
              BUF[k2][mi], bh[2 * (G) + k2][ni], acc[mi][ni], 0, 0, 0);        \
  }

    LOADQ(ahA, 0);

    // ---- x MFMAs (bx from LDS) overlap the first h-load flight ----
#pragma unroll
    for (int ksx = 0; ksx < 4; ksx++) {
      bf16x8 bxf[2];
#pragma unroll
      for (int ni = 0; ni < 2; ni++)
        bxf[ni] = *reinterpret_cast<const bf16x8*>(
            bxl + (((size_t)(((kq * 4 + ksx) * 2 + nh) * 2 + ni)) * 64 + lane) * 16);
#pragma unroll
      for (int mi = 0; mi < 4; mi++)
#pragma unroll
        for (int ni = 0; ni < 2; ni++)
          acc[mi][ni] = __builtin_amdgcn_mfma_f32_16x16x32_bf16(ax[ksx][mi], bxf[ni], acc[mi][ni], 0, 0, 0);
    }

    LOADQ(ahB, 1); MFMAQ(ahA, 0);
    LOADQ(ahA, 2); MFMAQ(ahB, 1);
    LOADQ(ahB, 3); MFMAQ(ahA, 2);
    MFMAQ(ahB, 3);
#undef LOADQ
#undef MFMAQ

    // ---- write per-wave partials: [kq][col 64][69] f32 (conflict-free) ----
    {
      float* pw = ldsP + kq * (64 * 69);
#pragma unroll
      for (int mi = 0; mi < 4; mi++)
#pragma unroll
        for (int ni = 0; ni < 2; ni++) {
          int col = nh * 32 + ni * 16 + ar;
          *reinterpret_cast<f32x4*>(pw + col * 69 + mi * 16 + h4 * 4) = acc[mi][ni];
        }
    }
    __syncthreads();

    // ---- reduce 4 partials + gating (thread: 1 row, 2 h-cols) ----
    float h0v, h1v;
    {
      float gi0 = b_i.x, gi1 = b_i.y, gf0 = b_f.x, gf1 = b_f.y;
      float gg0 = b_g.x, gg1 = b_g.y, go0 = b_o.x, go1 = b_o.y;
#pragma unroll
      for (int k4 = 0; k4 < 4; k4++) {
        const float* p2 = ldsP + k4 * (64 * 69);
        gi0 += p2[(0 * 16 + jl0) * 69 + rrow]; gi1 += p2[(0 * 16 + jl0 + 1) * 69 + rrow];
        gf0 += p2[(1 * 16 + jl0) * 69 + rrow]; gf1 += p2[(1 * 16 + jl0 + 1) * 69 + rrow];
        gg0 += p2[(2 * 16 + jl0) * 69 + rrow]; gg1 += p2[(2 * 16 + jl0 + 1) * 69 + rrow];
        go0 += p2[(3 * 16 + jl0) * 69 + rrow]; go1 += p2[(3 * 16 + jl0 + 1) * 69 + rrow];
      }
      float i0 = 1.f / (1.f + __expf(-gi0)), i1 = 1.f / (1.f + __expf(-gi1));
      float f0 = 1.f / (1.f + __expf(-gf0)), f1 = 1.f / (1.f + __expf(-gf1));
      float g0 = tanhf(gg0), g1 = tanhf(gg1);
      float o0 = 1.f / (1.f + __expf(-go0)), o1 = 1.f / (1.f + __expf(-go1));
      cst0 = f0 * cst0 + i0 * g0;
      cst1 = f1 * cst1 + i1 * g1;
      h0v = o0 * tanhf(cst0);
      h1v = o1 * tanhf(cst1);

      // publish h for step s+1 (fragment order, write-through to LLC)
      unsigned hp = (unsigned)f2b(h0v) | ((unsigned)f2b(h1v) << 16);
      u16* hD = hfrag + ((size_t)((s + 1) * 4 + dir * 2 + mt)) * 65536;
      __hip_atomic_store(reinterpret_cast<unsigned*>(hD + poff),
                         hp, __ATOMIC_RELAXED, __HIP_MEMORY_SCOPE_AGENT);
    }

    // ---- release: ack h stores -> all waves done -> post flag ----
    asm volatile("s_waitcnt vmcnt(0)" ::: "memory");
    __syncthreads();
    if (tid == 0)
      __hip_atomic_store(mypost, (unsigned)(s + 1),
                         __ATOMIC_RELAXED, __HIP_MEMORY_SCOPE_AGENT);

    // ---- y stores AFTER the release (off the critical path) ----
    {
      float2 yv; yv.x = h0v; yv.y = h1v;
      *reinterpret_cast<float2*>(out + ((size_t)t * BATCH + row0) * (2 * HDIM)
                                     + (size_t)dir * HDIM + jg0) = yv;
      if (s == T_STEPS - 1) {
        size_t hid = (size_t)T_STEPS * BATCH * 2 * HDIM;
        size_t base2 = hid + (size_t)dir * 2 * BATCH * HDIM;
        *reinterpret_cast<float2*>(out + base2 + (size_t)row0 * HDIM + jg0) = yv;
        float2 cv; cv.x = cst0; cv.y = cst1;
        *reinterpret_cast<float2*>(out + base2 + (size_t)BATCH * HDIM
                                       + (size_t)row0 * HDIM + jg0) = cv;
      }
    }
  }
}

extern "C" void kernel_launch(void* const* d_in, const int* in_sizes, int n_in,
                              void* d_out, int out_size, void* d_ws, size_t ws_size,
                              hipStream_t stream) {
  const float* x     = (const float*)d_in[0];
  const float* h0f   = (const float*)d_in[1];
  const float* c0f   = (const float*)d_in[2];
  const float* h0r   = (const float*)d_in[3];
  const float* c0r   = (const float*)d_in[4];
  const float* Wih_f = (const float*)d_in[5];
  const float* Whh_f = (const float*)d_in[6];
  const float* bih_f = (const float*)d_in[7];
  const float* bhh_f = (const float*)d_in[8];
  const float* Wih_r = (const float*)d_in[9];
  const float* Whh_r = (const float*)d_in[10];
  const float* bih_r = (const float*)d_in[11];
  const float* bhh_r = (const float*)d_in[12];
  float* out = (float*)d_out;
  char* ws = (char*)d_ws;

  if (ws_size < WS_NEED) return;

  u16* xsf        = (u16*)(ws + OFF_XBF);
  u16* Bm         = (u16*)(ws + OFF_BM);
  float* bias     = (float*)(ws + OFF_BIAS);
  unsigned* flags = (unsigned*)(ws + OFF_CNT);
  u16* hfrag      = (u16*)(ws + OFF_ROLL);

  k_cast_x<<<8192, 256, 0, stream>>>(x, xsf);
  k_build_b<<<128, 256, 0, stream>>>(Whh_f, Wih_f, Whh_r, Wih_r, Bm);
  k_init<<<1024, 256, 0, stream>>>(h0f, h0r, bih_f, bhh_f, bih_r, bhh_r,
                                   hfrag, bias, flags);
  k_lstm<<<256, 512, 0, stream>>>(xsf, Bm, hfrag, bias, flags, c0f, c0r, out);
}

// Round 15
// 2180.200 us; speedup vs baseline: 1.1305x; 1.1305x over previous
//
#include <hip/hip_runtime.h>
#include <hip/hip_bf16.h>

typedef unsigned short u16;
typedef __attribute__((ext_vector_type(8))) short bf16x8;
typedef __attribute__((ext_vector_type(8))) u16   u16x8;
typedef __attribute__((ext_vector_type(4))) float f32x4;

#define T_STEPS 256
#define BATCH   128
#define INDIM   512
#define HDIM    1024
#define GDIM    4096
#define KTOT    1536

#define OFF_XBF   ((size_t)0)
#define XBF_BYTES ((size_t)T_STEPS * BATCH * INDIM * 2)   // 33554432 (fragment-order)
#define OFF_BM    (OFF_XBF + XBF_BYTES)
#define BM_BYTES  ((size_t)2 * GDIM * KTOT * 2)           // 25165824 (fragment-order)
#define OFF_BIAS  (OFF_BM + BM_BYTES)
#define BIAS_BYTES ((size_t)2 * GDIM * 4)                 // 32768
#define OFF_CNT   (OFF_BIAS + BIAS_BYTES)
#define OFF_ROLL  (OFF_CNT + 8192)
#define ROLL_BYTES ((size_t)(T_STEPS + 1) * 2 * BATCH * HDIM * 2)  // 134742016
#define WS_NEED   (OFF_ROLL + ROLL_BYTES)

__device__ __forceinline__ u16 f2b(float f) {
  __hip_bfloat16 h = __float2bfloat16(f);
  return *reinterpret_cast<u16*>(&h);
}

// async global->LDS, 16B per lane (dest = wave-uniform base + lane*16)
__device__ __forceinline__ void glds16(const void* g, void* l) {
  __builtin_amdgcn_global_load_lds(
      (const __attribute__((address_space(1))) unsigned int*)g,
      (__attribute__((address_space(3))) unsigned int*)l, 16, 0, 0);
}

// ---------------- prepass: shuffle x (f32) into bf16 MFMA-fragment order ----
// xs block per (t,mt): 32768 elems; elem = (((kq*4+ksx)*4+mi)*64 + h4*16+ar)*8 + e
__global__ void k_cast_x(const float* __restrict__ x, u16* __restrict__ xs) {
  int i = blockIdx.x * 256 + threadIdx.x;      // one 8-elem fragment per thread
  int t   = i >> 13;                           // 8192 frags per t
  int r13 = i & 8191;
  int row = r13 >> 6;                          // 0..127
  int c0  = (r13 & 63) * 8;                    // 0..504
  int mt = row >> 6, rloc = row & 63;
  int mi = rloc >> 4, ar = rloc & 15;
  int kq = c0 >> 7, ksx = (c0 >> 5) & 3, h4 = (c0 & 31) >> 3;
  const float* src = x + ((size_t)t * BATCH + row) * INDIM + c0;
  f32x4 a = *reinterpret_cast<const f32x4*>(src);
  f32x4 b = *reinterpret_cast<const f32x4*>(src + 4);
  u16x8 u;
  u[0] = f2b(a[0]); u[1] = f2b(a[1]); u[2] = f2b(a[2]); u[3] = f2b(a[3]);
  u[4] = f2b(b[0]); u[5] = f2b(b[1]); u[6] = f2b(b[2]); u[7] = f2b(b[3]);
  size_t dst = ((size_t)(t * 2 + mt)) * 32768
             + (((size_t)((kq * 4 + ksx) * 4 + mi)) * 64 + h4 * 16 + ar) * 8;
  *reinterpret_cast<u16x8*>(xs + dst) = u;
}

// ---------------- prepass: build weight panels in MFMA-FRAGMENT ORDER ----
// Per (dir,jt) panel: 98304 elems. Col c (0..63) -> gate row G=(c>>4)*1024+jt*16+(c&15).
// c decomposed as nh=c>>5, ni=(c>>4)&1, ar=c&15.
// h-part (k<1024): off = ((((kq*8+ks)*2+nh)*2+ni)*64 + h4*16+ar)*8 + e
// x-part (k>=1024): off = 65536 + ((((kq2*4+ksx)*2+nh)*2+ni)*64 + h4*16+ar)*8 + e
__global__ void k_build_b(const float* __restrict__ Whh_f, const float* __restrict__ Wih_f,
                          const float* __restrict__ Whh_r, const float* __restrict__ Wih_r,
                          u16* __restrict__ Bm) {
  int blk = blockIdx.x;              // 0..127 = dir*64 + jt
  int dir = blk >> 6, jt = blk & 63;
  const float* Whh = dir ? Whh_r : Whh_f;
  const float* Wih = dir ? Wih_r : Wih_f;
  u16* dst = Bm + (size_t)blk * 98304;
  for (int c = 0; c < 64; c++) {
    int G  = (c >> 4) * HDIM + jt * 16 + (c & 15);
    int nh = c >> 5, ni = (c >> 4) & 1, ar = c & 15;
    for (int k = threadIdx.x; k < KTOT; k += 256) {
      size_t off;
      float v;
      if (k < HDIM) {
        int kq = k >> 8, ks = (k >> 5) & 7, h4 = (k & 31) >> 3, e = k & 7;
        off = ((((size_t)(kq * 8 + ks) * 2 + nh) * 2 + ni) * 64 + h4 * 16 + ar) * 8 + e;
        v = Whh[(size_t)G * HDIM + k];
      } else {
        int kx = k - HDIM;
        int kq2 = kx >> 7, ksx = (kx >> 5) & 3, h4 = (kx & 31) >> 3, e = kx & 7;
        off = 65536 + ((((size_t)(kq2 * 4 + ksx) * 2 + nh) * 2 + ni) * 64 + h4 * 16 + ar) * 8 + e;
        v = Wih[(size_t)G * INDIM + kx];
      }
      dst[off] = f2b(v);
    }
  }
}

// ---------------- prepass: init roll slot 0 (SWIZZLED), bias, flags ----------
__global__ void k_init(const float* __restrict__ h0f, const float* __restrict__ h0r,
                       const float* __restrict__ bihf, const float* __restrict__ bhhf,
                       const float* __restrict__ bihr, const float* __restrict__ bhhr,
                       u16* __restrict__ hroll, float* __restrict__ bias,
                       unsigned* __restrict__ flags) {
  int i = blockIdx.x * 256 + threadIdx.x;
  if (i < 2 * BATCH * HDIM) {
    int dir = i / (BATCH * HDIM);
    int rem = i - dir * BATCH * HDIM;
    int r = rem / HDIM, c = rem - r * HDIM;
    const float* h0 = dir ? h0r : h0f;
    char* hb = (char*)hroll;
    *(u16*)(hb + ((size_t)dir * BATCH + r) * 2048 + ((2 * c) ^ ((r & 7) << 4))) =
        f2b(h0[rem]);
  }
  if (i < 2 * GDIM) {
    int dir = i / GDIM, g = i - dir * GDIM;
    bias[i] = dir ? (bihr[g] + bhhr[g]) : (bihf[g] + bhhf[g]);
  }
  if (i < 512) flags[i] = 0;
}

// ---------------- persistent bidirectional LSTM ----------------
// R9 chassis: grid 256 x 512 (1 WG/CU), chain=(dir,mt) on XCD pair, h staged
// via global_load_lds from pre-swizzled roll, swizzled ds_read_b128 fragments.
// NEW: ALL weight loads (bh/bx, remat'd or not) are fragment-ordered coalesced
// 1KB bursts. Geometry 4 K-split x 2 N-split; partials [4][64][69] in the
// stage region (131KB total LDS).
__global__ __launch_bounds__(512, 2) void k_lstm(
    const u16* __restrict__ xs, const u16* __restrict__ Bm,
    u16* __restrict__ hroll,
    const float* __restrict__ bias, unsigned* __restrict__ flags,
    const float* __restrict__ c0f, const float* __restrict__ c0r,
    float* __restrict__ out) {
  __shared__ char ldsc[131072];    // h-stage 64x2048B  U  partials [4][64][69] f32
  float* ldsP = reinterpret_cast<float*>(ldsc);

  // Invalidate stale L1/L2 lines from a previous graph replay.
  __builtin_amdgcn_fence(__ATOMIC_ACQUIRE, "agent");

  const int wg   = blockIdx.x;
  const int xcd  = wg & 7, local = wg >> 3;    // round-robin XCD dispatch
  const int grp  = xcd >> 1;                   // 0..3 = (dir,mt) chain
  const int dir  = grp >> 1, mt = grp & 1;
  const int jt   = ((xcd & 1) << 5) | local;   // 0..63
  const int tid  = threadIdx.x;
  const int w = tid >> 6, lane = tid & 63;
  const int kq = w >> 1, nh = w & 1;           // 4-way K x 2-way N
  const int h4 = lane >> 4, kk = h4 * 8;
  const int ar = lane & 15;

  // ---- weight fragments, FRAGMENT-ORDERED panel (coalesced even if remat) ----
  const u16* bp = Bm + (size_t)(dir * 64 + jt) * 98304;
  bf16x8 bh[8][2], bx[4][2];
#pragma unroll
  for (int ks = 0; ks < 8; ks++)
#pragma unroll
    for (int ni = 0; ni < 2; ni++)
      bh[ks][ni] = *reinterpret_cast<const bf16x8*>(
          bp + ((((size_t)(kq * 8 + ks) * 2 + nh) * 2 + ni) * 64 + lane) * 8);
#pragma unroll
  for (int ksx = 0; ksx < 4; ksx++)
#pragma unroll
    for (int ni = 0; ni < 2; ni++)
      bx[ksx][ni] = *reinterpret_cast<const bf16x8*>(
          bp + 65536 + ((((size_t)(kq * 4 + ksx) * 2 + nh) * 2 + ni) * 64 + lane) * 8);

  // ---- gating thread mapping: 1 row x 2 adjacent cols per thread ----
  const int rrow = tid >> 3;            // 0..63 local row
  const int jl0  = 2 * (tid & 7);       // 0..14 even
  const int row0 = mt * 64 + rrow;      // global batch row
  const int jg0  = jt * 16 + jl0;       // global h column (even)
  const float* c0 = dir ? c0r : c0f;
  float2 cc = *reinterpret_cast<const float2*>(c0 + (size_t)row0 * HDIM + jg0);
  float cst0 = cc.x, cst1 = cc.y;
  const float2 b_i = *reinterpret_cast<const float2*>(bias + dir * GDIM + 0 * HDIM + jg0);
  const float2 b_f = *reinterpret_cast<const float2*>(bias + dir * GDIM + 1 * HDIM + jg0);
  const float2 b_g = *reinterpret_cast<const float2*>(bias + dir * GDIM + 2 * HDIM + jg0);
  const float2 b_o = *reinterpret_cast<const float2*>(bias + dir * GDIM + 3 * HDIM + jg0);

  const unsigned* fpA = flags + grp * 64 + lane;  // all 64 producers, one/lane

#pragma unroll 1
  for (int s = 0; s < T_STEPS; s++) {
    const int t = dir ? (T_STEPS - 1 - s) : s;

    // ---- x fragment loads (coalesced 1KB bursts), issued before the wait ----
    bf16x8 ax[4][4];
    {
      const u16* xb = xs + ((size_t)(t * 2 + mt)) * 32768;
#pragma unroll
      for (int ksx = 0; ksx < 4; ksx++)
#pragma unroll
        for (int mi = 0; mi < 4; mi++)
          ax[ksx][mi] = *reinterpret_cast<const bf16x8*>(
              xb + (((size_t)((kq * 4 + ksx) * 4 + mi)) * 64 + lane) * 8);
    }

    // ---- wait for ALL 64 producers of this chain (cooperative staging) ----
    if (s > 0) {
      while (true) {
        unsigned f = __hip_atomic_load(fpA, __ATOMIC_RELAXED, __HIP_MEMORY_SCOPE_AGENT);
        if (__all((int)(f >= (unsigned)s))) break;
        __builtin_amdgcn_s_sleep(1);
      }
      __builtin_amdgcn_sched_barrier(0);   // keep glds below the wait
    }

    // ---- stage h tile (128KB, pre-swizzled bytes, linear copy) ----
    {
      const char* hRd = (const char*)(hroll + ((size_t)s * 2 + dir) * BATCH * HDIM
                                            + (size_t)mt * 64 * HDIM);
      unsigned off = (unsigned)tid * 16;
#pragma unroll
      for (int i = 0; i < 16; i++)
        glds16(hRd + off + i * 8192, ldsc + off + i * 8192);
    }
    __builtin_amdgcn_sched_barrier(0);   // keep x-MFMAs below glds issue

    // ---- x MFMAs overlap the glds flight ----
    f32x4 acc[4][2];
#pragma unroll
    for (int mi = 0; mi < 4; mi++)
#pragma unroll
      for (int ni = 0; ni < 2; ni++) acc[mi][ni] = f32x4{0.f, 0.f, 0.f, 0.f};
#pragma unroll
    for (int ksx = 0; ksx < 4; ksx++)
#pragma unroll
      for (int mi = 0; mi < 4; mi++)
#pragma unroll
        for (int ni = 0; ni < 2; ni++)
          acc[mi][ni] = __builtin_amdgcn_mfma_f32_16x16x32_bf16(ax[ksx][mi], bx[ksx][ni], acc[mi][ni], 0, 0, 0);

    __syncthreads();   // drains glds; h tile resident in LDS

    // ---- h phase: swizzled conflict-free ds_read_b128 + MFMA ----
#pragma unroll
    for (int ks = 0; ks < 8; ks++) {
      bf16x8 af[4];
#pragma unroll
      for (int mi = 0; mi < 4; mi++) {
        unsigned row = 16 * mi + ar;
        unsigned cb = (256 * kq + 32 * ks + kk) * 2;
        af[mi] = *reinterpret_cast<const bf16x8*>(
            ldsc + row * 2048 + (cb ^ ((row & 7) << 4)));
      }
#pragma unroll
      for (int mi = 0; mi < 4; mi++)
#pragma unroll
        for (int ni = 0; ni < 2; ni++)
          acc[mi][ni] = __builtin_amdgcn_mfma_f32_16x16x32_bf16(af[mi], bh[ks][ni], acc[mi][ni], 0, 0, 0);
    }
    __syncthreads();   // h-LDS dead; partials may overwrite

    // ---- write per-wave partials: [kq][col 64][69] f32 (conflict-free) ----
    {
      float* pw = ldsP + kq * (64 * 69);
#pragma unroll
      for (int mi = 0; mi < 4; mi++)
#pragma unroll
        for (int ni = 0; ni < 2; ni++) {
          int col = nh * 32 + ni * 16 + ar;
          *reinterpret_cast<f32x4*>(pw + col * 69 + mi * 16 + h4 * 4) = acc[mi][ni];
        }
    }
    __syncthreads();

    // ---- reduce 4 partials + gating (thread: 1 row, 2 cols) ----
    float h0v, h1v;
    {
      float gi0 = b_i.x, gi1 = b_i.y, gf0 = b_f.x, gf1 = b_f.y;
      float gg0 = b_g.x, gg1 = b_g.y, go0 = b_o.x, go1 = b_o.y;
#pragma unroll
      for (int k4 = 0; k4 < 4; k4++) {
        const float* p = ldsP + k4 * (64 * 69);
        gi0 += p[(0 * 16 + jl0) * 69 + rrow]; gi1 += p[(0 * 16 + jl0 + 1) * 69 + rrow];
        gf0 += p[(1 * 16 + jl0) * 69 + rrow]; gf1 += p[(1 * 16 + jl0 + 1) * 69 + rrow];
        gg0 += p[(2 * 16 + jl0) * 69 + rrow]; gg1 += p[(2 * 16 + jl0 + 1) * 69 + rrow];
        go0 += p[(3 * 16 + jl0) * 69 + rrow]; go1 += p[(3 * 16 + jl0 + 1) * 69 + rrow];
      }
      float i0 = 1.f / (1.f + __expf(-gi0)), i1 = 1.f / (1.f + __expf(-gi1));
      float f0 = 1.f / (1.f + __expf(-gf0)), f1 = 1.f / (1.f + __expf(-gf1));
      float g0 = tanhf(gg0), g1 = tanhf(gg1);
      float o0 = 1.f / (1.f + __expf(-go0)), o1 = 1.f / (1.f + __expf(-go1));
      cst0 = f0 * cst0 + i0 * g0;
      cst1 = f1 * cst1 + i1 * g1;
      h0v = o0 * tanhf(cst0);
      h1v = o1 * tanhf(cst1);

      // publish h for step s+1 (SWIZZLED layout, write-through to LLC)
      unsigned hp = (unsigned)f2b(h0v) | ((unsigned)f2b(h1v) << 16);
      char* hb = (char*)(hroll + ((size_t)(s + 1) * 2 + dir) * BATCH * HDIM);
      __hip_atomic_store(
          (unsigned*)(hb + (size_t)row0 * 2048 + ((2 * jg0) ^ ((row0 & 7) << 4))),
          hp, __ATOMIC_RELAXED, __HIP_MEMORY_SCOPE_AGENT);
    }

    // ---- release: ack h stores -> all waves done -> post flag ----
    asm volatile("s_waitcnt vmcnt(0)" ::: "memory");
    __syncthreads();
    if (tid == 0)
      __hip_atomic_store(flags + grp * 64 + jt, (unsigned)(s + 1),
                         __ATOMIC_RELAXED, __HIP_MEMORY_SCOPE_AGENT);

    // ---- y stores AFTER the release (off the critical path) ----
    {
      float2 yv; yv.x = h0v; yv.y = h1v;
      *reinterpret_cast<float2*>(out + ((size_t)t * BATCH + row0) * (2 * HDIM)
                                     + (size_t)dir * HDIM + jg0) = yv;
      if (s == T_STEPS - 1) {
        size_t hid = (size_t)T_STEPS * BATCH * 2 * HDIM;
        size_t base2 = hid + (size_t)dir * 2 * BATCH * HDIM;
        *reinterpret_cast<float2*>(out + base2 + (size_t)row0 * HDIM + jg0) = yv;
        float2 cv; cv.x = cst0; cv.y = cst1;
        *reinterpret_cast<float2*>(out + base2 + (size_t)BATCH * HDIM
                                       + (size_t)row0 * HDIM + jg0) = cv;
      }
    }
  }
}

extern "C" void kernel_launch(void* const* d_in, const int* in_sizes, int n_in,
                              void* d_out, int out_size, void* d_ws, size_t ws_size,
                              hipStream_t stream) {
  const float* x     = (const float*)d_in[0];
  const float* h0f   = (const float*)d_in[1];
  const float* c0f   = (const float*)d_in[2];
  const float* h0r   = (const float*)d_in[3];
  const float* c0r   = (const float*)d_in[4];
  const float* Wih_f = (const float*)d_in[5];
  const float* Whh_f = (const float*)d_in[6];
  const float* bih_f = (const float*)d_in[7];
  const float* bhh_f = (const float*)d_in[8];
  const float* Wih_r = (const float*)d_in[9];
  const float* Whh_r = (const float*)d_in[10];
  const float* bih_r = (const float*)d_in[11];
  const float* bhh_r = (const float*)d_in[12];
  float* out = (float*)d_out;
  char* ws = (char*)d_ws;

  if (ws_size < WS_NEED) return;

  u16* xsf        = (u16*)(ws + OFF_XBF);
  u16* Bm         = (u16*)(ws + OFF_BM);
  float* bias     = (float*)(ws + OFF_BIAS);
  unsigned* flags = (unsigned*)(ws + OFF_CNT);
  u16* hroll      = (u16*)(ws + OFF_ROLL);

  k_cast_x<<<8192, 256, 0, stream>>>(x, xsf);
  k_build_b<<<128, 256, 0, stream>>>(Whh_f, Wih_f, Whh_r, Wih_r, Bm);
  k_init<<<1024, 256, 0, stream>>>(h0f, h0r, bih_f, bhh_f, bih_r, bhh_r,
                                   hroll, bias, flags);
  k_lstm<<<256, 512, 0, stream>>>(xsf, Bm, hroll, bias, flags, c0f, c0r, out);
}

// Round 16
// 2038.498 us; speedup vs baseline: 1.2091x; 1.0695x over previous
//
#include <hip/hip_runtime.h>
#include <hip/hip_bf16.h>

typedef unsigned short u16;
typedef __attribute__((ext_vector_type(8))) short bf16x8;
typedef __attribute__((ext_vector_type(8))) u16   u16x8;
typedef __attribute__((ext_vector_type(4))) float f32x4;

#define T_STEPS 256
#define BATCH   128
#define INDIM   512
#define HDIM    1024
#define GDIM    4096
#define KTOT    1536

#define OFF_XBF   ((size_t)0)
#define XBF_BYTES ((size_t)T_STEPS * BATCH * INDIM * 2)   // 33554432
#define OFF_BM    (OFF_XBF + XBF_BYTES)
#define BM_BYTES  ((size_t)2 * GDIM * KTOT * 2)           // 25165824
#define OFF_BIAS  (OFF_BM + BM_BYTES)
#define BIAS_BYTES ((size_t)2 * GDIM * 4)                 // 32768
#define OFF_CNT   (OFF_BIAS + BIAS_BYTES)
#define OFF_ROLL  (OFF_CNT + 8192)
#define ROLL_BYTES ((size_t)(T_STEPS + 1) * 2 * BATCH * HDIM * 2)  // 134742016
#define WS_NEED   (OFF_ROLL + ROLL_BYTES)

__device__ __forceinline__ u16 f2b(float f) {
  __hip_bfloat16 h = __float2bfloat16(f);
  return *reinterpret_cast<u16*>(&h);
}

// async global->LDS, 16B per lane (dest = wave-uniform base + lane*16)
__device__ __forceinline__ void glds16(const void* g, void* l) {
  __builtin_amdgcn_global_load_lds(
      (const __attribute__((address_space(1))) unsigned int*)g,
      (__attribute__((address_space(3))) unsigned int*)l, 16, 0, 0);
}

// ---------------- prepass: cast x to bf16 ----------------
__global__ void k_cast_x(const float* __restrict__ x, u16* __restrict__ xb) {
  size_t i = ((size_t)blockIdx.x * 256 + threadIdx.x) * 8;
  f32x4 a = *reinterpret_cast<const f32x4*>(x + i);
  f32x4 b = *reinterpret_cast<const f32x4*>(x + i + 4);
  u16x8 u;
  u[0] = f2b(a[0]); u[1] = f2b(a[1]); u[2] = f2b(a[2]); u[3] = f2b(a[3]);
  u[4] = f2b(b[0]); u[5] = f2b(b[1]); u[6] = f2b(b[2]); u[7] = f2b(b[3]);
  *reinterpret_cast<u16x8*>(xb + i) = u;
}

// ---------------- prepass: build merged weight matrix ----------------
// Bm[dir][jt][c 0..63][k 0..1535] bf16; col c -> gate row G=(c>>4)*1024+jt*16+(c&15)
__global__ void k_build_b(const float* __restrict__ Whh_f, const float* __restrict__ Wih_f,
                          const float* __restrict__ Whh_r, const float* __restrict__ Wih_r,
                          u16* __restrict__ Bm) {
  int blk = blockIdx.x;              // 0..127 = dir*64 + jt
  int dir = blk >> 6, jt = blk & 63;
  const float* Whh = dir ? Whh_r : Whh_f;
  const float* Wih = dir ? Wih_r : Wih_f;
  u16* dst = Bm + (size_t)blk * 64 * KTOT;
  for (int c = 0; c < 64; c++) {
    int G = (c >> 4) * HDIM + jt * 16 + (c & 15);
    for (int k = threadIdx.x; k < KTOT; k += 256) {
      float v = (k < HDIM) ? Whh[(size_t)G * HDIM + k] : Wih[(size_t)G * INDIM + (k - HDIM)];
      dst[c * KTOT + k] = f2b(v);
    }
  }
}

// ---------------- prepass: init roll slot 0 (SWIZZLED), bias, flags ----------------
__global__ void k_init(const float* __restrict__ h0f, const float* __restrict__ h0r,
                       const float* __restrict__ bihf, const float* __restrict__ bhhf,
                       const float* __restrict__ bihr, const float* __restrict__ bhhr,
                       u16* __restrict__ hroll, float* __restrict__ bias,
                       unsigned* __restrict__ flags) {
  int i = blockIdx.x * 256 + threadIdx.x;
  if (i < 2 * BATCH * HDIM) {
    int dir = i / (BATCH * HDIM);
    int rem = i - dir * BATCH * HDIM;
    int r = rem / HDIM, c = rem - r * HDIM;
    const float* h0 = dir ? h0r : h0f;
    char* hb = (char*)hroll;
    *(u16*)(hb + ((size_t)dir * BATCH + r) * 2048 + ((2 * c) ^ ((r & 7) << 4))) =
        f2b(h0[rem]);
  }
  if (i < 2 * GDIM) {
    int dir = i / GDIM, g = i - dir * GDIM;
    bias[i] = dir ? (bihr[g] + bhhr[g]) : (bihf[g] + bhhf[g]);
  }
  if (i < 512) flags[i] = 0;
}

// ---------------- persistent bidirectional LSTM ----------------
// grid 256 WGs x 512 thr (1/CU). WG=(dir,mt,jt): M=64 x N=64 x K=1536, 8-wave
// K-split, Bh in regs. h tile staged via global_load_lds from a PRE-SWIZZLED
// roll buffer (byte ^= (row&7)<<4 within each 2048B row), fragments via
// conflict-free swizzled ds_read_b128. x-MFMAs overlap the stage flight.
__global__ __launch_bounds__(512, 2) void k_lstm(
    const u16* __restrict__ xb, const u16* __restrict__ Bm,
    u16* __restrict__ hroll,
    const float* __restrict__ bias, unsigned* __restrict__ flags,
    const float* __restrict__ c0f, const float* __restrict__ c0r,
    float* __restrict__ out) {
  __shared__ float ldsf[8 * 64 * 68];   // 139264B: h-stage [0,131072) U partials
  char* ldsc = reinterpret_cast<char*>(ldsf);

  // Invalidate stale L1/L2 lines from a previous graph replay.
  __builtin_amdgcn_fence(__ATOMIC_ACQUIRE, "agent");

  const int wg   = blockIdx.x;
  const int xcd  = wg & 7, local = wg >> 3;    // round-robin XCD dispatch
  const int grp  = xcd >> 1;                   // 0..3 = (dir,mt) chain
  const int dir  = grp >> 1, mt = grp & 1;
  const int jt   = ((xcd & 1) << 5) | local;   // 0..63
  const int tid = threadIdx.x;
  const int w = tid >> 6, lane = tid & 63;
  const int kk = (lane >> 4) * 8;
  const int ar = lane & 15;

  // ---- persistent h-part weight fragments in registers ----
  const u16* bsrc = Bm + (size_t)(dir * 64 + jt) * 64 * KTOT;
  bf16x8 bh[4][4];
#pragma unroll
  for (int ks = 0; ks < 4; ks++)
#pragma unroll
    for (int ni = 0; ni < 4; ni++)
      bh[ks][ni] = *reinterpret_cast<const bf16x8*>(
          bsrc + (size_t)(ni * 16 + ar) * KTOT + 128 * w + 32 * ks + kk);

  // ---- gating thread mapping: 1 row x 2 adjacent cols per thread ----
  const int rrow = tid >> 3;            // 0..63 local row
  const int cp   = tid & 7;             // col pair 0..7
  const int jl0  = 2 * cp;
  const int row0 = mt * 64 + rrow;      // global batch row
  const int jg0  = jt * 16 + jl0;       // global h column (even)
  const float* c0 = dir ? c0r : c0f;
  float2 cc = *reinterpret_cast<const float2*>(c0 + (size_t)row0 * HDIM + jg0);
  float cst0 = cc.x, cst1 = cc.y;
  const float2 b_i = *reinterpret_cast<const float2*>(bias + dir * GDIM + 0 * HDIM + jg0);
  const float2 b_f = *reinterpret_cast<const float2*>(bias + dir * GDIM + 1 * HDIM + jg0);
  const float2 b_g = *reinterpret_cast<const float2*>(bias + dir * GDIM + 2 * HDIM + jg0);
  const float2 b_o = *reinterpret_cast<const float2*>(bias + dir * GDIM + 3 * HDIM + jg0);

  const unsigned* fpA = flags + grp * 64 + lane;  // all 64 producers, one/lane

#pragma unroll 1
  for (int s = 0; s < T_STEPS; s++) {
    const int t = dir ? (T_STEPS - 1 - s) : s;

    // ---- issue x-loads FIRST (older than glds in vmcnt FIFO) ----
    bf16x8 axm[2][4], bxn[2][4];
    {
      const u16* xsrc = xb + ((size_t)t * BATCH + mt * 64) * INDIM;
#pragma unroll
      for (int ks = 0; ks < 2; ks++) {
#pragma unroll
        for (int mi = 0; mi < 4; mi++)
          axm[ks][mi] = *reinterpret_cast<const bf16x8*>(
              xsrc + (size_t)(16 * mi + ar) * INDIM + 64 * w + 32 * ks + kk);
#pragma unroll
        for (int ni = 0; ni < 4; ni++)
          bxn[ks][ni] = *reinterpret_cast<const bf16x8*>(
              bsrc + (size_t)(ni * 16 + ar) * KTOT + HDIM + 64 * w + 32 * ks + kk);
      }
    }

    // ---- wait for ALL 64 producers of this chain (cooperative staging) ----
    if (s > 0) {
      while (true) {
        unsigned f = __hip_atomic_load(fpA, __ATOMIC_RELAXED, __HIP_MEMORY_SCOPE_AGENT);
        if (__all((int)(f >= (unsigned)s))) break;
        __builtin_amdgcn_s_sleep(1);
      }
      __builtin_amdgcn_sched_barrier(0);   // keep glds below the wait
    }

    // ---- stage h tile (128KB, pre-swizzled bytes, linear copy) ----
    {
      const char* hRd = (const char*)(hroll + ((size_t)s * 2 + dir) * BATCH * HDIM
                                            + (size_t)mt * 64 * HDIM);
      unsigned off = (unsigned)w * 1024 + (unsigned)(lane * 16);
#pragma unroll
      for (int i = 0; i < 16; i++)
        glds16(hRd + off + i * 8192, ldsc + off + i * 8192);
    }

    // ---- x MFMAs overlap the glds flight (waitcnt stops at x-loads) ----
    f32x4 acc[4][4];
#pragma unroll
    for (int mi = 0; mi < 4; mi++)
#pragma unroll
      for (int ni = 0; ni < 4; ni++) acc[mi][ni] = f32x4{0.f, 0.f, 0.f, 0.f};
#pragma unroll
    for (int ks = 0; ks < 2; ks++)
#pragma unroll
      for (int mi = 0; mi < 4; mi++)
#pragma unroll
        for (int ni = 0; ni < 4; ni++)
          acc[mi][ni] = __builtin_amdgcn_mfma_f32_16x16x32_bf16(axm[ks][mi], bxn[ks][ni], acc[mi][ni], 0, 0, 0);

    __syncthreads();   // drains glds; h tile resident in LDS

    // ---- h phase: swizzled conflict-free ds_read_b128 + MFMA ----
#pragma unroll
    for (int ks = 0; ks < 4; ks++)
#pragma unroll
      for (int mi = 0; mi < 4; mi++) {
        unsigned row = 16 * mi + ar;
        unsigned cb = (128 * w + 32 * ks + kk) * 2;
        bf16x8 af = *reinterpret_cast<const bf16x8*>(
            ldsc + row * 2048 + (cb ^ ((row & 7) << 4)));
#pragma unroll
        for (int ni = 0; ni < 4; ni++)
          acc[mi][ni] = __builtin_amdgcn_mfma_f32_16x16x32_bf16(af, bh[ks][ni], acc[mi][ni], 0, 0, 0);
      }
    __syncthreads();   // h-LDS dead; partials may overwrite

    // ---- write per-wave partials: [w][c 64][68 r] f32, col-major ----
    {
      float* pw = ldsf + w * (64 * 68);
#pragma unroll
      for (int mi = 0; mi < 4; mi++)
#pragma unroll
        for (int ni = 0; ni < 4; ni++)
          *reinterpret_cast<f32x4*>(pw + (ni * 16 + ar) * 68 + mi * 16 + (lane >> 4) * 4) = acc[mi][ni];
    }
    __syncthreads();

    // ---- reduce 8 partials + gating (thread: 1 row, 2 cols) ----
    float h0v, h1v;
    {
      float gi0 = b_i.x, gi1 = b_i.y, gf0 = b_f.x, gf1 = b_f.y;
      float gg0 = b_g.x, gg1 = b_g.y, go0 = b_o.x, go1 = b_o.y;
#pragma unroll
      for (int ww = 0; ww < 8; ww++) {
        const float* p = ldsf + ww * (64 * 68);
        gi0 += p[(0 * 16 + jl0) * 68 + rrow]; gi1 += p[(0 * 16 + jl0 + 1) * 68 + rrow];
        gf0 += p[(1 * 16 + jl0) * 68 + rrow]; gf1 += p[(1 * 16 + jl0 + 1) * 68 + rrow];
        gg0 += p[(2 * 16 + jl0) * 68 + rrow]; gg1 += p[(2 * 16 + jl0 + 1) * 68 + rrow];
        go0 += p[(3 * 16 + jl0) * 68 + rrow]; go1 += p[(3 * 16 + jl0 + 1) * 68 + rrow];
      }
      float i0 = 1.f / (1.f + __expf(-gi0)), i1 = 1.f / (1.f + __expf(-gi1));
      float f0 = 1.f / (1.f + __expf(-gf0)), f1 = 1.f / (1.f + __expf(-gf1));
      float g0 = tanhf(gg0), g1 = tanhf(gg1);
      float o0 = 1.f / (1.f + __expf(-go0)), o1 = 1.f / (1.f + __expf(-go1));
      cst0 = f0 * cst0 + i0 * g0;
      cst1 = f1 * cst1 + i1 * g1;
      h0v = o0 * tanhf(cst0);
      h1v = o1 * tanhf(cst1);

      // publish h for step s+1 (SWIZZLED layout, write-through to LLC)
      unsigned hp = (unsigned)f2b(h0v) | ((unsigned)f2b(h1v) << 16);
      char* hb = (char*)(hroll + ((size_t)(s + 1) * 2 + dir) * BATCH * HDIM);
      __hip_atomic_store(
          (unsigned*)(hb + (size_t)row0 * 2048 + ((2 * jg0) ^ ((row0 & 7) << 4))),
          hp, __ATOMIC_RELAXED, __HIP_MEMORY_SCOPE_AGENT);
    }

    // ---- release: ack h stores -> all waves done -> post flag ----
    asm volatile("s_waitcnt vmcnt(0)" ::: "memory");
    __syncthreads();
    if (tid == 0)
      __hip_atomic_store(flags + grp * 64 + jt, (unsigned)(s + 1),
                         __ATOMIC_RELAXED, __HIP_MEMORY_SCOPE_AGENT);

    // ---- y stores AFTER the release (off the critical path) ----
    {
      float2 yv; yv.x = h0v; yv.y = h1v;
      *reinterpret_cast<float2*>(out + ((size_t)t * BATCH + row0) * (2 * HDIM)
                                     + (size_t)dir * HDIM + jg0) = yv;
      if (s == T_STEPS - 1) {
        size_t hid = (size_t)T_STEPS * BATCH * 2 * HDIM;
        size_t base2 = hid + (size_t)dir * 2 * BATCH * HDIM;
        *reinterpret_cast<float2*>(out + base2 + (size_t)row0 * HDIM + jg0) = yv;
        float2 cv; cv.x = cst0; cv.y = cst1;
        *reinterpret_cast<float2*>(out + base2 + (size_t)BATCH * HDIM
                                       + (size_t)row0 * HDIM + jg0) = cv;
      }
    }
  }
}

extern "C" void kernel_launch(void* const* d_in, const int* in_sizes, int n_in,
                              void* d_out, int out_size, void* d_ws, size_t ws_size,
                              hipStream_t stream) {
  const float* x     = (const float*)d_in[0];
  const float* h0f   = (const float*)d_in[1];
  const float* c0f   = (const float*)d_in[2];
  const float* h0r   = (const float*)d_in[3];
  const float* c0r   = (const float*)d_in[4];
  const float* Wih_f = (const float*)d_in[5];
  const float* Whh_f = (const float*)d_in[6];
  const float* bih_f = (const float*)d_in[7];
  const float* bhh_f = (const float*)d_in[8];
  const float* Wih_r = (const float*)d_in[9];
  const float* Whh_r = (const float*)d_in[10];
  const float* bih_r = (const float*)d_in[11];
  const float* bhh_r = (const float*)d_in[12];
  float* out = (float*)d_out;
  char* ws = (char*)d_ws;

  if (ws_size < WS_NEED) return;

  u16* xbf        = (u16*)(ws + OFF_XBF);
  u16* Bm         = (u16*)(ws + OFF_BM);
  float* bias     = (float*)(ws + OFF_BIAS);
  unsigned* flags = (unsigned*)(ws + OFF_CNT);
  u16* hroll      = (u16*)(ws + OFF_ROLL);

  k_cast_x<<<8192, 256, 0, stream>>>(x, xbf);
  k_build_b<<<128, 256, 0, stream>>>(Whh_f, Wih_f, Whh_r, Wih_r, Bm);
  k_init<<<1024, 256, 0, stream>>>(h0f, h0r, bih_f, bhh_f, bih_r, bhh_r,
                                   hroll, bias, flags);
  k_lstm<<<256, 512, 0, stream>>>(xbf, Bm, hroll, bias, flags, c0f, c0r, out);
}